// Round 8
// baseline (231.372 us; speedup 1.0000x reference)
//
#include <hip/hip_runtime.h>

#define HW 4096
#define KC 512

typedef __attribute__((ext_vector_type(8))) short s16x8;
typedef __attribute__((ext_vector_type(16))) float f32x16;

__device__ inline short f2bf(float f) {          // RTNE float->bf16
    unsigned int u = __builtin_bit_cast(unsigned int, f);
    unsigned int lsb = (u >> 16) & 1u;
    u += 0x7fffu + lsb;
    return (short)(u >> 16);
}
__device__ inline float bf2f(short h) {
    unsigned int u = ((unsigned int)(unsigned short)h) << 16;
    return __builtin_bit_cast(float, u);
}

// ws byte layout:
//   0       cnt f32[512]                  (zeroed)
//   2048    avg f32[32768]                (zeroed)
//   133120  loss f32[1]                   (zeroed)
//   133136  en f32[512]
//   135184  ehfrag short[16*5*64*8]  80KB (codes hi + en hi/lo cols, K=80)
//   217104  elfrag short[16*4*64*8]  64KB (codes lo, K=64)
//   282640  idx u16[131072]
#define WS_EN    133136
#define WS_EHF   135184
#define WS_ELF   217104
#define WS_IDX   282640

__global__ void k_prep_en(const float* __restrict__ emb, float* __restrict__ en) {
    int m = blockIdx.x * 256 + threadIdx.x;
    if (m >= KC) return;
    const float* e = emb + m * 64;
    float d0 = 0.f, d1 = 0.f, d2 = 0.f, d3 = 0.f;
#pragma unroll
    for (int c = 0; c < 64; c += 4) {
        d0 = fmaf(e[c], e[c], d0);
        d1 = fmaf(e[c + 1], e[c + 1], d1);
        d2 = fmaf(e[c + 2], e[c + 2], d2);
        d3 = fmaf(e[c + 3], e[c + 3], d3);
    }
    en[m] = (d0 + d1) + (d2 + d3);
}

// Build pre-swizzled A-fragments (32x32x16 layout: m=lane&31, k=(lane>>5)*8+j).
__global__ void k_prep_frag(const float* __restrict__ emb, const float* __restrict__ en,
                            short* __restrict__ ehf, short* __restrict__ elf) {
    int t = blockIdx.x * 256 + threadIdx.x;   // 0..4095
    int m = t >> 3, ko = t & 7;
    int mt = m >> 5, ks = ko >> 1;
    int lane = (m & 31) + 32 * (ko & 1);
    s16x8 hv, lv;
#pragma unroll
    for (int j = 0; j < 8; ++j) {
        float v = emb[m * 64 + ko * 8 + j];
        short h = f2bf(v);
        hv[j] = h;
        lv[j] = f2bf(v - bf2f(h));
    }
    ((s16x8*)ehf)[(mt * 5 + ks) * 64 + lane] = hv;
    ((s16x8*)elf)[(mt * 4 + ks) * 64 + lane] = lv;

    // ks=4 block of ehf: k=64 -> en_hi, k=65 -> en_lo, rest 0. One u32 per thread.
    int e2 = t * 2;
    int mt2 = e2 >> 9;
    int lane2 = (e2 >> 3) & 63;
    int j2 = e2 & 7;
    unsigned int val = 0;
    if (lane2 < 32 && j2 == 0) {
        float ev = en[mt2 * 32 + (lane2 & 31)];
        short eh_ = f2bf(ev);
        short el_ = f2bf(ev - bf2f(eh_));
        val = ((unsigned int)(unsigned short)eh_) | (((unsigned int)(unsigned short)el_) << 16);
    }
    *(unsigned int*)(ehf + ((size_t)(mt2 * 5 + 4) * 64 + lane2) * 8 + j2) = val;
}

__device__ inline void merge2(float& s1, int& i1, float& s2, int& i2,
                              float os1, int oi1, float os2, int oi2) {
    bool ob = (os1 < s1) || (os1 == s1 && oi1 < i1);
    float n1s = ob ? os1 : s1;  int n1i = ob ? oi1 : i1;
    float ls  = ob ? s1  : os1; int li  = ob ? i1  : oi1;  // losing first
    float ws  = ob ? os2 : s2;  int wi  = ob ? oi2 : i2;   // winner's second
    bool b2 = (ls < ws) || (ls == ws && li < wi);
    s1 = n1s; i1 = n1i;
    s2 = b2 ? ls : ws; i2 = b2 ? li : wi;
}

// 256 threads = 4 independent waves (no LDS, no barriers).
// Each wave: 32 tokens x 512 codes (grid 1024 blocks -> 4096 waves = 4/SIMD).
// waves_per_eu(4,4) PINS occupancy target so the compiler uses the full
// 128-VGPR budget (R6's launch_bounds(256,4) starved it to 64 VGPR).
__global__ __attribute__((amdgpu_flat_work_group_size(256, 256),
                          amdgpu_waves_per_eu(4, 4)))
void k_main(const float* __restrict__ x,
            const short* __restrict__ ehf,
            const short* __restrict__ elf,
            const float* __restrict__ en,
            const float* __restrict__ emb,
            float* __restrict__ qout,
            unsigned short* __restrict__ idx_out,
            float* __restrict__ loss_acc) {
    int tid = threadIdx.x;
    int wv = tid >> 6, lane = tid & 63;
    int tb = blockIdx.x * 128;                 // 128 tokens per block
    int n = tb >> 12, hwb = tb & 4095;
    const float* xp = x + (size_t)n * 64 * HW;
    int wbase = hwb + wv * 32;

    int l5 = lane & 31;
    int kh = (lane >> 5) * 8;    // k-half channel offset

    // ---- direct-to-fragment loads of x~ (hi/lo bf16) ----
    s16x8 fh[5], fl[4];
    {
        const float* pa = xp + wbase + l5;
#pragma unroll
        for (int ks = 0; ks < 4; ++ks) {
            s16x8 ha, la;
#pragma unroll
            for (int j = 0; j < 8; ++j) {
                int c = ks * 16 + kh + j;
                float va = -2.0f * pa[(size_t)c * HW];
                short h0 = f2bf(va); ha[j] = h0; la[j] = f2bf(va - bf2f(h0));
            }
            fh[ks] = ha; fl[ks] = la;
        }
        s16x8 v0;
#pragma unroll
        for (int j = 0; j < 8; ++j) v0[j] = 0;
        if (lane < 32) { v0[0] = (short)0x3F80; v0[1] = (short)0x3F80; }
        fh[4] = v0;
    }

    const s16x8* eh8 = (const s16x8*)ehf;
    const s16x8* el8 = (const s16x8*)elf;

    float s1 = 3.402823466e38f, s2 = 3.402823466e38f;
    int i1 = 0, i2 = 0;
    int hv4 = (lane >> 5) * 4;

#pragma unroll 2
    for (int mt = 0; mt < 16; ++mt) {
        s16x8 ah[5], al[4];
#pragma unroll
        for (int ks = 0; ks < 5; ++ks) ah[ks] = eh8[(mt * 5 + ks) * 64 + lane];
#pragma unroll
        for (int ks = 0; ks < 4; ++ks) al[ks] = el8[(mt * 4 + ks) * 64 + lane];

        f32x16 acc;
#pragma unroll
        for (int r = 0; r < 16; ++r) acc[r] = 0.0f;
#pragma unroll
        for (int ks = 0; ks < 5; ++ks)
            acc = __builtin_amdgcn_mfma_f32_32x32x16_bf16(ah[ks], fh[ks], acc, 0, 0, 0);
#pragma unroll
        for (int ks = 0; ks < 4; ++ks)
            acc = __builtin_amdgcn_mfma_f32_32x32x16_bf16(al[ks], fh[ks], acc, 0, 0, 0);
#pragma unroll
        for (int ks = 0; ks < 4; ++ks)
            acc = __builtin_amdgcn_mfma_f32_32x32x16_bf16(ah[ks], fl[ks], acc, 0, 0, 0);

        int mb = mt * 32 + hv4;
#pragma unroll
        for (int r = 0; r < 16; ++r) {
            int mi = mb + (r & 3) + 8 * (r >> 2);
            float s = acc[r];
            bool c1 = s < s1, c2 = s < s2;
            s2 = c1 ? s1 : (c2 ? s : s2); i2 = c1 ? i1 : (c2 ? mi : i2);
            s1 = c1 ? s : s1;             i1 = c1 ? mi : i1;
        }
    }

    // lanes l and l^32 hold disjoint code-rows of the same token column: merge
    merge2(s1, i1, s2, i2, __shfl_xor(s1, 32), __shfl_xor(i1, 32),
           __shfl_xor(s2, 32), __shfl_xor(i2, 32));

    int ia = (i1 < i2) ? i1 : i2;
    int ib = (i1 < i2) ? i2 : i1;

    // ---- exact fp32 rescore; the two half-lanes of a token split channels ----
    int coff = (lane >> 5) * 32;           // this lane's channel half
    const float* xq = xp + wbase + l5;
    float xh[32];
#pragma unroll
    for (int j = 0; j < 32; ++j) xh[j] = xq[(size_t)(coff + j) * HW];

    float sxx;
    {
        float d0 = 0.f, d1 = 0.f, d2 = 0.f, d3 = 0.f;
#pragma unroll
        for (int j = 0; j < 32; j += 4) {
            d0 = fmaf(xh[j], xh[j], d0);
            d1 = fmaf(xh[j + 1], xh[j + 1], d1);
            d2 = fmaf(xh[j + 2], xh[j + 2], d2);
            d3 = fmaf(xh[j + 3], xh[j + 3], d3);
        }
        float part = (d0 + d1) + (d2 + d3);
        float oth = __shfl_xor(part, 32);
        sxx = (lane < 32) ? (part + oth) : (oth + part);
    }

    float da, db;
    {
        const float4* er = (const float4*)(emb + (size_t)ia * 64) + (coff >> 2);
        float d0 = 0.f, d1 = 0.f, d2 = 0.f, d3 = 0.f;
#pragma unroll
        for (int q = 0; q < 8; ++q) {
            float4 e4 = er[q];
            d0 = fmaf(xh[q * 4], e4.x, d0);
            d1 = fmaf(xh[q * 4 + 1], e4.y, d1);
            d2 = fmaf(xh[q * 4 + 2], e4.z, d2);
            d3 = fmaf(xh[q * 4 + 3], e4.w, d3);
        }
        float part = (d0 + d1) + (d2 + d3);
        float oth = __shfl_xor(part, 32);
        da = (lane < 32) ? (part + oth) : (oth + part);
    }
    {
        const float4* er = (const float4*)(emb + (size_t)ib * 64) + (coff >> 2);
        float d0 = 0.f, d1 = 0.f, d2 = 0.f, d3 = 0.f;
#pragma unroll
        for (int q = 0; q < 8; ++q) {
            float4 e4 = er[q];
            d0 = fmaf(xh[q * 4], e4.x, d0);
            d1 = fmaf(xh[q * 4 + 1], e4.y, d1);
            d2 = fmaf(xh[q * 4 + 2], e4.z, d2);
            d3 = fmaf(xh[q * 4 + 3], e4.w, d3);
        }
        float part = (d0 + d1) + (d2 + d3);
        float oth = __shfl_xor(part, 32);
        db = (lane < 32) ? (part + oth) : (oth + part);
    }
    float sa = (sxx + en[ia]) - 2.0f * da;
    float sb = (sxx + en[ib]) - 2.0f * db;
    int win = (sb < sa) ? ib : ia;   // tie -> lower index (ia < ib)

    if (lane < 32) idx_out[tb + wv * 32 + l5] = (unsigned short)win;

    // quantized write + loss (each lane: its 32 channels of its token)
    const float4* ew = (const float4*)(emb + (size_t)win * 64) + (coff >> 2);
    float* qp = qout + (size_t)n * 64 * HW + wbase + l5;
    float l0 = 0.f, l1 = 0.f, l2 = 0.f, l3 = 0.f;
#pragma unroll
    for (int q = 0; q < 8; ++q) {
        float4 e4 = ew[q];
        int c = coff + q * 4;
        qp[(size_t)c * HW] = e4.x;
        qp[(size_t)(c + 1) * HW] = e4.y;
        qp[(size_t)(c + 2) * HW] = e4.z;
        qp[(size_t)(c + 3) * HW] = e4.w;
        float f0 = xh[q * 4] - e4.x, f1 = xh[q * 4 + 1] - e4.y;
        float f2 = xh[q * 4 + 2] - e4.z, f3 = xh[q * 4 + 3] - e4.w;
        l0 = fmaf(f0, f0, l0);
        l1 = fmaf(f1, f1, l1);
        l2 = fmaf(f2, f2, l2);
        l3 = fmaf(f3, f3, l3);
    }
    float lp = (l0 + l1) + (l2 + l3);
#pragma unroll
    for (int off = 32; off; off >>= 1) lp += __shfl_down(lp, off);
    if (lane == 0) atomicAdd(loss_acc, lp);
}

// grid = (32 images) x (8 channel-groups); LDS acc [512][9] (9 coprime to 32).
__global__ __launch_bounds__(1024) void k_seg(const float* __restrict__ x,
                                              const unsigned short* __restrict__ idx,
                                              float* __restrict__ cnt_g,
                                              float* __restrict__ avg_g) {
    __shared__ float acc[KC * 9];
    __shared__ float cnt[KC];
    int tid = threadIdx.x;
    int n = blockIdx.x >> 3;
    int cg = blockIdx.x & 7;

    for (int i = tid; i < KC * 9; i += 1024) acc[i] = 0.f;
    if (cg == 0 && tid < KC) cnt[tid] = 0.f;
    __syncthreads();

    const float* xp = x + (size_t)n * 64 * HW + (size_t)(cg * 8) * HW;
    const unsigned short* ip = idx + n * HW;

#pragma unroll
    for (int p = 0; p < 4; ++p) {
        int hw = p * 1024 + tid;
        int k = ip[hw];
        if (cg == 0) atomicAdd(&cnt[k], 1.0f);
        float* row = acc + k * 9;
#pragma unroll
        for (int j = 0; j < 8; ++j) {
            atomicAdd(&row[j], xp[(size_t)j * HW + hw]);
        }
    }
    __syncthreads();

    for (int i = tid; i < KC * 8; i += 1024) {
        int k = i >> 3, j = i & 7;
        atomicAdd(&avg_g[k * 64 + cg * 8 + j], acc[k * 9 + j]);
    }
    if (cg == 0 && tid < KC) atomicAdd(&cnt_g[tid], cnt[tid]);
}

__global__ void k_fin(const float* __restrict__ cs_in, const float* __restrict__ avg_in,
                      const float* __restrict__ cnt, const float* __restrict__ avgacc,
                      const float* __restrict__ loss_acc,
                      float* __restrict__ loss_out, float* __restrict__ emb_out,
                      float* __restrict__ cs_out, float* __restrict__ avg_out) {
    int i = blockIdx.x * 256 + threadIdx.x;
    if (i >= KC * 64) return;
    int k = i >> 6, c = i & 63;
    float ncs = cs_in[k] * 0.99f + 0.01f * cnt[k];
    float nav = avg_in[i] * 0.99f + 0.01f * avgacc[i];
    avg_out[i] = nav;
    emb_out[i] = nav / (ncs + 1e-5f);
    if (c == 0) cs_out[k] = ncs;
    if (i == 0) loss_out[0] = loss_acc[0] * (1.0f / 8388608.0f);
}

extern "C" void kernel_launch(void* const* d_in, const int* in_sizes, int n_in,
                              void* d_out, int out_size, void* d_ws, size_t ws_size,
                              hipStream_t stream) {
    (void)in_sizes; (void)n_in; (void)out_size; (void)ws_size;
    const float* x   = (const float*)d_in[0];
    const float* emb = (const float*)d_in[1];
    const float* cs  = (const float*)d_in[2];
    const float* avg = (const float*)d_in[3];

    float* out      = (float*)d_out;
    float* qout     = out;
    float* loss_out = out + 8388608;
    float* emb_out  = loss_out + 1;
    float* cs_out   = emb_out + 32768;
    float* avg_out  = cs_out + 512;

    char* wsb = (char*)d_ws;
    float* cnt_acc  = (float*)wsb;
    float* avg_acc  = (float*)(wsb + 2048);
    float* loss_acc = (float*)(wsb + 133120);
    float* en       = (float*)(wsb + WS_EN);
    short* ehf      = (short*)(wsb + WS_EHF);
    short* elf      = (short*)(wsb + WS_ELF);
    unsigned short* idx = (unsigned short*)(wsb + WS_IDX);

    hipMemsetAsync(d_ws, 0, 133124, stream);
    k_prep_en<<<2, 256, 0, stream>>>(emb, en);
    k_prep_frag<<<16, 256, 0, stream>>>(emb, en, ehf, elf);
    k_main<<<1024, 256, 0, stream>>>(x, ehf, elf, en, emb, qout, idx, loss_acc);
    k_seg<<<256, 1024, 0, stream>>>(x, idx, cnt_acc, avg_acc);
    k_fin<<<128, 256, 0, stream>>>(cs, avg, cnt_acc, avg_acc, loss_acc,
                                   loss_out, emb_out, cs_out, avg_out);
}

// Round 9
// 139.457 us; speedup vs baseline: 1.6591x; 1.6591x over previous
//
#include <hip/hip_runtime.h>

#define HW 4096
#define KC 512

typedef __attribute__((ext_vector_type(8))) short s16x8;
typedef __attribute__((ext_vector_type(16))) float f32x16;

__device__ inline short f2bf(float f) {          // RTNE float->bf16
    unsigned int u = __builtin_bit_cast(unsigned int, f);
    unsigned int lsb = (u >> 16) & 1u;
    u += 0x7fffu + lsb;
    return (short)(u >> 16);
}
__device__ inline float bf2f(short h) {
    unsigned int u = ((unsigned int)(unsigned short)h) << 16;
    return __builtin_bit_cast(float, u);
}

// ws byte layout:
//   0       cnt f32[512]                  (zeroed)
//   2048    avg f32[32768]                (zeroed)
//   133120  loss f32[1]                   (zeroed)
//   133136  en f32[512]
//   135184  ehfrag short[16*5*64*8]  80KB (codes hi + en hi/lo cols, K=80)
//   217104  elfrag short[16*4*64*8]  64KB (codes lo, K=64)
//   282640  idx u16[131072]
#define WS_EN    133136
#define WS_EHF   135184
#define WS_ELF   217104
#define WS_IDX   282640

__global__ void k_prep_en(const float* __restrict__ emb, float* __restrict__ en) {
    int m = blockIdx.x * 256 + threadIdx.x;
    if (m >= KC) return;
    const float* e = emb + m * 64;
    float d0 = 0.f, d1 = 0.f, d2 = 0.f, d3 = 0.f;
#pragma unroll
    for (int c = 0; c < 64; c += 4) {
        d0 = fmaf(e[c], e[c], d0);
        d1 = fmaf(e[c + 1], e[c + 1], d1);
        d2 = fmaf(e[c + 2], e[c + 2], d2);
        d3 = fmaf(e[c + 3], e[c + 3], d3);
    }
    en[m] = (d0 + d1) + (d2 + d3);
}

// Build pre-swizzled A-fragments (32x32x16 layout: m=lane&31, k=(lane>>5)*8+j).
__global__ void k_prep_frag(const float* __restrict__ emb, const float* __restrict__ en,
                            short* __restrict__ ehf, short* __restrict__ elf) {
    int t = blockIdx.x * 256 + threadIdx.x;   // 0..4095
    int m = t >> 3, ko = t & 7;
    int mt = m >> 5, ks = ko >> 1;
    int lane = (m & 31) + 32 * (ko & 1);
    s16x8 hv, lv;
#pragma unroll
    for (int j = 0; j < 8; ++j) {
        float v = emb[m * 64 + ko * 8 + j];
        short h = f2bf(v);
        hv[j] = h;
        lv[j] = f2bf(v - bf2f(h));
    }
    ((s16x8*)ehf)[(mt * 5 + ks) * 64 + lane] = hv;
    ((s16x8*)elf)[(mt * 4 + ks) * 64 + lane] = lv;

    // ks=4 block of ehf: k=64 -> en_hi, k=65 -> en_lo, rest 0. One u32 per thread.
    int e2 = t * 2;
    int mt2 = e2 >> 9;
    int lane2 = (e2 >> 3) & 63;
    int j2 = e2 & 7;
    unsigned int val = 0;
    if (lane2 < 32 && j2 == 0) {
        float ev = en[mt2 * 32 + (lane2 & 31)];
        short eh_ = f2bf(ev);
        short el_ = f2bf(ev - bf2f(eh_));
        val = ((unsigned int)(unsigned short)eh_) | (((unsigned int)(unsigned short)el_) << 16);
    }
    *(unsigned int*)(ehf + ((size_t)(mt2 * 5 + 4) * 64 + lane2) * 8 + j2) = val;
}

__device__ inline void merge2(float& s1, int& i1, float& s2, int& i2,
                              float os1, int oi1, float os2, int oi2) {
    bool ob = (os1 < s1) || (os1 == s1 && oi1 < i1);
    float n1s = ob ? os1 : s1;  int n1i = ob ? oi1 : i1;
    float ls  = ob ? s1  : os1; int li  = ob ? i1  : oi1;  // losing first
    float ws  = ob ? os2 : s2;  int wi  = ob ? oi2 : i2;   // winner's second
    bool b2 = (ls < ws) || (ls == ws && li < wi);
    s1 = n1s; i1 = n1i;
    s2 = b2 ? ls : ws; i2 = b2 ? li : wi;
}

// 512 threads = 8 waves, 1 block/CU. The 144KB pre-swizzled codebook fragment
// set is staged ONCE into LDS (block-invariant), one barrier, then 8
// independent waves (64 tokens each) read A-frags via ds_read_b128
// (conflict-free linear layout) instead of per-wave L2 gathers. No barriers
// in the hot loop. B-frags of x~ = -2x (hi/lo bf16) direct from global.
__global__ __launch_bounds__(512, 2) void k_main(const float* __restrict__ x,
                                              const short* __restrict__ ehf,
                                              const short* __restrict__ elf,
                                              const float* __restrict__ en,
                                              const float* __restrict__ emb,
                                              float* __restrict__ qout,
                                              unsigned short* __restrict__ idx_out,
                                              float* __restrict__ loss_acc) {
    __shared__ short shH[16 * 5 * 64 * 8];   // 80 KB
    __shared__ short shL[16 * 4 * 64 * 8];   // 64 KB

    int tid = threadIdx.x;
    int wv = tid >> 6, lane = tid & 63;
    int tb = blockIdx.x * 512;
    int n = tb >> 12, hwb = tb & 4095;
    const float* xp = x + (size_t)n * 64 * HW;
    int wbase = hwb + wv * 64;

    // ---- stage codebook fragments into LDS (coalesced, once) ----
    {
        const s16x8* ehg = (const s16x8*)ehf;   // 5120 elems
        const s16x8* elg = (const s16x8*)elf;   // 4096 elems
        s16x8* sH = (s16x8*)shH;
        s16x8* sL = (s16x8*)shL;
#pragma unroll
        for (int i = 0; i < 10; ++i) sH[i * 512 + tid] = ehg[i * 512 + tid];
#pragma unroll
        for (int i = 0; i < 8; ++i) sL[i * 512 + tid] = elg[i * 512 + tid];
    }

    int l5 = lane & 31;
    int kh = (lane >> 5) * 8;    // k-half channel offset

    // ---- direct-to-fragment loads of x~ (hi/lo bf16), overlaps staging ----
    s16x8 fah[5], fbh[5], fal[4], fbl[4];
    {
        const float* pa = xp + wbase + l5;
        const float* pb = pa + 32;
#pragma unroll
        for (int ks = 0; ks < 4; ++ks) {
            s16x8 ha, la, hb, lb;
#pragma unroll
            for (int j = 0; j < 8; ++j) {
                int c = ks * 16 + kh + j;
                float va = -2.0f * pa[(size_t)c * HW];
                float vb = -2.0f * pb[(size_t)c * HW];
                short h0 = f2bf(va); ha[j] = h0; la[j] = f2bf(va - bf2f(h0));
                short h1 = f2bf(vb); hb[j] = h1; lb[j] = f2bf(vb - bf2f(h1));
            }
            fah[ks] = ha; fal[ks] = la; fbh[ks] = hb; fbl[ks] = lb;
        }
        s16x8 v0;
#pragma unroll
        for (int j = 0; j < 8; ++j) v0[j] = 0;
        if (lane < 32) { v0[0] = (short)0x3F80; v0[1] = (short)0x3F80; }
        fah[4] = v0; fbh[4] = v0;
    }

    __syncthreads();

    const s16x8* sH8 = (const s16x8*)shH;
    const s16x8* sL8 = (const s16x8*)shL;

    float s1a = 3.402823466e38f, s2a = 3.402823466e38f;
    float s1b = 3.402823466e38f, s2b = 3.402823466e38f;
    int i1a = 0, i2a = 0, i1b = 0, i2b = 0;
    int hv4 = (lane >> 5) * 4;

#pragma unroll 2
    for (int mt = 0; mt < 16; ++mt) {
        s16x8 ah[5], al[4];
#pragma unroll
        for (int ks = 0; ks < 5; ++ks) ah[ks] = sH8[(mt * 5 + ks) * 64 + lane];
#pragma unroll
        for (int ks = 0; ks < 4; ++ks) al[ks] = sL8[(mt * 4 + ks) * 64 + lane];

        f32x16 acc0, acc1;
#pragma unroll
        for (int r = 0; r < 16; ++r) { acc0[r] = 0.0f; acc1[r] = 0.0f; }
#pragma unroll
        for (int ks = 0; ks < 5; ++ks) {
            acc0 = __builtin_amdgcn_mfma_f32_32x32x16_bf16(ah[ks], fah[ks], acc0, 0, 0, 0);
            acc1 = __builtin_amdgcn_mfma_f32_32x32x16_bf16(ah[ks], fbh[ks], acc1, 0, 0, 0);
        }
#pragma unroll
        for (int ks = 0; ks < 4; ++ks) {
            acc0 = __builtin_amdgcn_mfma_f32_32x32x16_bf16(al[ks], fah[ks], acc0, 0, 0, 0);
            acc1 = __builtin_amdgcn_mfma_f32_32x32x16_bf16(al[ks], fbh[ks], acc1, 0, 0, 0);
        }
#pragma unroll
        for (int ks = 0; ks < 4; ++ks) {
            acc0 = __builtin_amdgcn_mfma_f32_32x32x16_bf16(ah[ks], fal[ks], acc0, 0, 0, 0);
            acc1 = __builtin_amdgcn_mfma_f32_32x32x16_bf16(ah[ks], fbl[ks], acc1, 0, 0, 0);
        }

        int mb = mt * 32 + hv4;
#pragma unroll
        for (int r = 0; r < 16; ++r) {
            int mi = mb + (r & 3) + 8 * (r >> 2);
            {
                float s = acc0[r];
                bool c1 = s < s1a, c2 = s < s2a;
                s2a = c1 ? s1a : (c2 ? s : s2a); i2a = c1 ? i1a : (c2 ? mi : i2a);
                s1a = c1 ? s : s1a;              i1a = c1 ? mi : i1a;
            }
            {
                float s = acc1[r];
                bool c1 = s < s1b, c2 = s < s2b;
                s2b = c1 ? s1b : (c2 ? s : s2b); i2b = c1 ? i1b : (c2 ? mi : i2b);
                s1b = c1 ? s : s1b;              i1b = c1 ? mi : i1b;
            }
        }
    }

    // lanes l and l^32 hold disjoint code-rows of the same token column: merge
    merge2(s1a, i1a, s2a, i2a, __shfl_xor(s1a, 32), __shfl_xor(i1a, 32),
           __shfl_xor(s2a, 32), __shfl_xor(i2a, 32));
    merge2(s1b, i1b, s2b, i2b, __shfl_xor(s1b, 32), __shfl_xor(i1b, 32),
           __shfl_xor(s2b, 32), __shfl_xor(i2b, 32));

    bool hi = (lane & 32) != 0;
    int I1 = hi ? i1b : i1a;
    int I2 = hi ? i2b : i2a;

    // ---- exact fp32 rescore of the two candidates (matches reference rounding) ----
    int hw = wbase + lane;
    const float* xq = xp + hw;
    float xv[64];
#pragma unroll
    for (int c = 0; c < 64; ++c) xv[c] = xq[(size_t)c * HW];

    float sxx;
    {
        float d0 = 0.f, d1 = 0.f, d2 = 0.f, d3 = 0.f;
#pragma unroll
        for (int c = 0; c < 64; c += 4) {
            d0 = fmaf(xv[c], xv[c], d0);
            d1 = fmaf(xv[c + 1], xv[c + 1], d1);
            d2 = fmaf(xv[c + 2], xv[c + 2], d2);
            d3 = fmaf(xv[c + 3], xv[c + 3], d3);
        }
        sxx = (d0 + d1) + (d2 + d3);
    }

    int ia = (I1 < I2) ? I1 : I2;
    int ib = (I1 < I2) ? I2 : I1;
    float sa, sb;
    {
        const float4* er = (const float4*)(emb + (size_t)ia * 64);
        float d0 = 0.f, d1 = 0.f, d2 = 0.f, d3 = 0.f;
#pragma unroll
        for (int q = 0; q < 16; ++q) {
            float4 e4 = er[q];
            d0 = fmaf(xv[q * 4], e4.x, d0);
            d1 = fmaf(xv[q * 4 + 1], e4.y, d1);
            d2 = fmaf(xv[q * 4 + 2], e4.z, d2);
            d3 = fmaf(xv[q * 4 + 3], e4.w, d3);
        }
        sa = (sxx + en[ia]) - 2.0f * ((d0 + d1) + (d2 + d3));
    }
    {
        const float4* er = (const float4*)(emb + (size_t)ib * 64);
        float d0 = 0.f, d1 = 0.f, d2 = 0.f, d3 = 0.f;
#pragma unroll
        for (int q = 0; q < 16; ++q) {
            float4 e4 = er[q];
            d0 = fmaf(xv[q * 4], e4.x, d0);
            d1 = fmaf(xv[q * 4 + 1], e4.y, d1);
            d2 = fmaf(xv[q * 4 + 2], e4.z, d2);
            d3 = fmaf(xv[q * 4 + 3], e4.w, d3);
        }
        sb = (sxx + en[ib]) - 2.0f * ((d0 + d1) + (d2 + d3));
    }
    int win = (sb < sa) ? ib : ia;   // tie -> lower index (ia < ib)

    idx_out[tb + wv * 64 + lane] = (unsigned short)win;

    // quantized write + loss
    const float4* ew = (const float4*)(emb + (size_t)win * 64);
    float* qp = qout + (size_t)n * 64 * HW + hw;
    float l0 = 0.f, l1 = 0.f, l2 = 0.f, l3 = 0.f;
#pragma unroll
    for (int q = 0; q < 16; ++q) {
        float4 e4 = ew[q];
        qp[(size_t)(q * 4) * HW] = e4.x;
        qp[(size_t)(q * 4 + 1) * HW] = e4.y;
        qp[(size_t)(q * 4 + 2) * HW] = e4.z;
        qp[(size_t)(q * 4 + 3) * HW] = e4.w;
        float f0 = xv[q * 4] - e4.x, f1 = xv[q * 4 + 1] - e4.y;
        float f2 = xv[q * 4 + 2] - e4.z, f3 = xv[q * 4 + 3] - e4.w;
        l0 = fmaf(f0, f0, l0);
        l1 = fmaf(f1, f1, l1);
        l2 = fmaf(f2, f2, l2);
        l3 = fmaf(f3, f3, l3);
    }
    float lp = (l0 + l1) + (l2 + l3);
#pragma unroll
    for (int off = 32; off; off >>= 1) lp += __shfl_down(lp, off);
    if (lane == 0) atomicAdd(loss_acc, lp);
}

// grid = (32 images) x (8 channel-groups) x (2 hw-halves) = 512 blocks.
// LDS acc [512][9] (9 coprime to 32 banks). 2 blocks/CU for latency overlap.
__global__ __launch_bounds__(1024) void k_seg(const float* __restrict__ x,
                                              const unsigned short* __restrict__ idx,
                                              float* __restrict__ cnt_g,
                                              float* __restrict__ avg_g) {
    __shared__ float acc[KC * 9];
    __shared__ float cnt[KC];
    int tid = threadIdx.x;
    int b = blockIdx.x;
    int n = b >> 4;
    int cg = (b >> 1) & 7;
    int h = b & 1;

    for (int i = tid; i < KC * 9; i += 1024) acc[i] = 0.f;
    if (cg == 0 && tid < KC) cnt[tid] = 0.f;
    __syncthreads();

    const float* xp = x + (size_t)n * 64 * HW + (size_t)(cg * 8) * HW + h * 2048;
    const unsigned short* ip = idx + n * HW + h * 2048;

#pragma unroll
    for (int p = 0; p < 2; ++p) {
        int hw = p * 1024 + tid;
        int k = ip[hw];
        if (cg == 0) atomicAdd(&cnt[k], 1.0f);
        float* row = acc + k * 9;
#pragma unroll
        for (int j = 0; j < 8; ++j) {
            atomicAdd(&row[j], xp[(size_t)j * HW + hw]);
        }
    }
    __syncthreads();

    for (int i = tid; i < KC * 8; i += 1024) {
        int k = i >> 3, j = i & 7;
        atomicAdd(&avg_g[k * 64 + cg * 8 + j], acc[k * 9 + j]);
    }
    if (cg == 0 && tid < KC) atomicAdd(&cnt_g[tid], cnt[tid]);
}

__global__ void k_fin(const float* __restrict__ cs_in, const float* __restrict__ avg_in,
                      const float* __restrict__ cnt, const float* __restrict__ avgacc,
                      const float* __restrict__ loss_acc,
                      float* __restrict__ loss_out, float* __restrict__ emb_out,
                      float* __restrict__ cs_out, float* __restrict__ avg_out) {
    int i = blockIdx.x * 256 + threadIdx.x;
    if (i >= KC * 64) return;
    int k = i >> 6, c = i & 63;
    float ncs = cs_in[k] * 0.99f + 0.01f * cnt[k];
    float nav = avg_in[i] * 0.99f + 0.01f * avgacc[i];
    avg_out[i] = nav;
    emb_out[i] = nav / (ncs + 1e-5f);
    if (c == 0) cs_out[k] = ncs;
    if (i == 0) loss_out[0] = loss_acc[0] * (1.0f / 8388608.0f);
}

extern "C" void kernel_launch(void* const* d_in, const int* in_sizes, int n_in,
                              void* d_out, int out_size, void* d_ws, size_t ws_size,
                              hipStream_t stream) {
    (void)in_sizes; (void)n_in; (void)out_size; (void)ws_size;
    const float* x   = (const float*)d_in[0];
    const float* emb = (const float*)d_in[1];
    const float* cs  = (const float*)d_in[2];
    const float* avg = (const float*)d_in[3];

    float* out      = (float*)d_out;
    float* qout     = out;
    float* loss_out = out + 8388608;
    float* emb_out  = loss_out + 1;
    float* cs_out   = emb_out + 32768;
    float* avg_out  = cs_out + 512;

    char* wsb = (char*)d_ws;
    float* cnt_acc  = (float*)wsb;
    float* avg_acc  = (float*)(wsb + 2048);
    float* loss_acc = (float*)(wsb + 133120);
    float* en       = (float*)(wsb + WS_EN);
    short* ehf      = (short*)(wsb + WS_EHF);
    short* elf      = (short*)(wsb + WS_ELF);
    unsigned short* idx = (unsigned short*)(wsb + WS_IDX);

    hipMemsetAsync(d_ws, 0, 133124, stream);
    k_prep_en<<<2, 256, 0, stream>>>(emb, en);
    k_prep_frag<<<16, 256, 0, stream>>>(emb, en, ehf, elf);
    k_main<<<256, 512, 0, stream>>>(x, ehf, elf, en, emb, qout, idx, loss_acc);
    k_seg<<<512, 1024, 0, stream>>>(x, idx, cnt_acc, avg_acc);
    k_fin<<<128, 256, 0, stream>>>(cs, avg, cnt_acc, avg_acc, loss_acc,
                                   loss_out, emb_out, cs_out, avg_out);
}

// Round 11
// 135.038 us; speedup vs baseline: 1.7134x; 1.0327x over previous
//
#include <hip/hip_runtime.h>

#define HW 4096
#define KC 512

typedef __attribute__((ext_vector_type(8))) short s16x8;
typedef __attribute__((ext_vector_type(16))) float f32x16;

__device__ inline short f2bf(float f) {          // RTNE float->bf16
    unsigned int u = __builtin_bit_cast(unsigned int, f);
    unsigned int lsb = (u >> 16) & 1u;
    u += 0x7fffu + lsb;
    return (short)(u >> 16);
}
__device__ inline float bf2f(short h) {
    unsigned int u = ((unsigned int)(unsigned short)h) << 16;
    return __builtin_bit_cast(float, u);
}

// ws byte layout:
//   0       cnt f32[512]                  (zeroed)
//   2048    avg f32[32768]                (zeroed)
//   133120  loss f32[1]                   (zeroed)
//   133136  en f32[512]
//   135184  ehfrag short[16*5*64*8]  80KB (codes hi + en hi/lo cols, K=80)
//   217104  elfrag short[16*4*64*8]  64KB (codes lo, K=64)
//   282640  idx u16[131072]
#define WS_EN    133136
#define WS_EHF   135184
#define WS_ELF   217104
#define WS_IDX   282640

__global__ void k_prep_en(const float* __restrict__ emb, float* __restrict__ en) {
    int m = blockIdx.x * 256 + threadIdx.x;
    if (m >= KC) return;
    const float* e = emb + m * 64;
    float d0 = 0.f, d1 = 0.f, d2 = 0.f, d3 = 0.f;
#pragma unroll
    for (int c = 0; c < 64; c += 4) {
        d0 = fmaf(e[c], e[c], d0);
        d1 = fmaf(e[c + 1], e[c + 1], d1);
        d2 = fmaf(e[c + 2], e[c + 2], d2);
        d3 = fmaf(e[c + 3], e[c + 3], d3);
    }
    en[m] = (d0 + d1) + (d2 + d3);
}

// Build pre-swizzled A-fragments (32x32x16 layout: m=lane&31, k=(lane>>5)*8+j).
__global__ void k_prep_frag(const float* __restrict__ emb, const float* __restrict__ en,
                            short* __restrict__ ehf, short* __restrict__ elf) {
    int t = blockIdx.x * 256 + threadIdx.x;   // 0..4095
    int m = t >> 3, ko = t & 7;
    int mt = m >> 5, ks = ko >> 1;
    int lane = (m & 31) + 32 * (ko & 1);
    s16x8 hv, lv;
#pragma unroll
    for (int j = 0; j < 8; ++j) {
        float v = emb[m * 64 + ko * 8 + j];
        short h = f2bf(v);
        hv[j] = h;
        lv[j] = f2bf(v - bf2f(h));
    }
    ((s16x8*)ehf)[(mt * 5 + ks) * 64 + lane] = hv;
    ((s16x8*)elf)[(mt * 4 + ks) * 64 + lane] = lv;

    // ks=4 block of ehf: k=64 -> en_hi, k=65 -> en_lo, rest 0. One u32 per thread.
    int e2 = t * 2;
    int mt2 = e2 >> 9;
    int lane2 = (e2 >> 3) & 63;
    int j2 = e2 & 7;
    unsigned int val = 0;
    if (lane2 < 32 && j2 == 0) {
        float ev = en[mt2 * 32 + (lane2 & 31)];
        short eh_ = f2bf(ev);
        short el_ = f2bf(ev - bf2f(eh_));
        val = ((unsigned int)(unsigned short)eh_) | (((unsigned int)(unsigned short)el_) << 16);
    }
    *(unsigned int*)(ehf + ((size_t)(mt2 * 5 + 4) * 64 + lane2) * 8 + j2) = val;
}

__device__ inline void merge2(float& s1, int& i1, float& s2, int& i2,
                              float os1, int oi1, float os2, int oi2) {
    bool ob = (os1 < s1) || (os1 == s1 && oi1 < i1);
    float n1s = ob ? os1 : s1;  int n1i = ob ? oi1 : i1;
    float ls  = ob ? s1  : os1; int li  = ob ? i1  : oi1;  // losing first
    float ws  = ob ? os2 : s2;  int wi  = ob ? oi2 : i2;   // winner's second
    bool b2 = (ls < ws) || (ls == ws && li < wi);
    s1 = n1s; i1 = n1i;
    s2 = b2 ? ls : ws; i2 = b2 ? li : wi;
}

// 512 threads = 8 waves, 1 block/CU (132KB LDS). LDS holds the fp32 codebook
// [512 rows x 66-float padded stride] + en at row offset 64 — so the
// lane-DIVERGENT epilogue reads (rescore + quantized-write, 48 row-gathers
// per wave) hit LDS instead of decomposing into 64-way-split L2 transactions.
// A-fragments read from L2 in the hot loop (R7 vs R9: L2 == LDS for those).
// No barriers in the hot loop.
__global__ __launch_bounds__(512, 2) void k_main(const float* __restrict__ x,
                                              const short* __restrict__ ehf,
                                              const short* __restrict__ elf,
                                              const float* __restrict__ en,
                                              const float* __restrict__ emb,
                                              float* __restrict__ qout,
                                              unsigned short* __restrict__ idx_out,
                                              float* __restrict__ loss_acc) {
    __shared__ float se[KC * 66];   // 135168 B

    int tid = threadIdx.x;
    int wv = tid >> 6, lane = tid & 63;
    int tb = blockIdx.x * 512;
    int n = tb >> 12, hwb = tb & 4095;
    const float* xp = x + (size_t)n * 64 * HW;
    int wbase = hwb + wv * 64;

    // ---- stage fp32 codebook (+en) into padded LDS, coalesced ----
    {
        const float2* eg = (const float2*)emb;   // 16384 float2
#pragma unroll
        for (int i = 0; i < 32; ++i) {
            int id2 = i * 512 + tid;
            int row = id2 >> 5, h = id2 & 31;
            float2 v = eg[id2];
            *(float2*)&se[row * 66 + h * 2] = v;
        }
        se[tid * 66 + 64] = en[tid];   // unique location per thread, no race
    }

    int l5 = lane & 31;
    int kh = (lane >> 5) * 8;    // k-half channel offset

    // ---- direct-to-fragment loads of x~ = -2x (hi/lo bf16), overlaps staging ----
    s16x8 fah[5], fbh[5], fal[4], fbl[4];
    {
        const float* pa = xp + wbase + l5;
        const float* pb = pa + 32;
#pragma unroll
        for (int ks = 0; ks < 4; ++ks) {
            s16x8 ha, la, hb, lb;
#pragma unroll
            for (int j = 0; j < 8; ++j) {
                int c = ks * 16 + kh + j;
                float va = -2.0f * pa[(size_t)c * HW];
                float vb = -2.0f * pb[(size_t)c * HW];
                short h0 = f2bf(va); ha[j] = h0; la[j] = f2bf(va - bf2f(h0));
                short h1 = f2bf(vb); hb[j] = h1; lb[j] = f2bf(vb - bf2f(h1));
            }
            fah[ks] = ha; fal[ks] = la; fbh[ks] = hb; fbl[ks] = lb;
        }
        s16x8 v0;
#pragma unroll
        for (int j = 0; j < 8; ++j) v0[j] = 0;
        if (lane < 32) { v0[0] = (short)0x3F80; v0[1] = (short)0x3F80; }
        fah[4] = v0; fbh[4] = v0;
    }

    __syncthreads();

    const s16x8* eh8 = (const s16x8*)ehf;
    const s16x8* el8 = (const s16x8*)elf;

    float s1a = 3.402823466e38f, s2a = 3.402823466e38f;
    float s1b = 3.402823466e38f, s2b = 3.402823466e38f;
    int i1a = 0, i2a = 0, i1b = 0, i2b = 0;
    int hv4 = (lane >> 5) * 4;

#pragma unroll 2
    for (int mt = 0; mt < 16; ++mt) {
        s16x8 ah[5], al[4];
#pragma unroll
        for (int ks = 0; ks < 5; ++ks) ah[ks] = eh8[(mt * 5 + ks) * 64 + lane];
#pragma unroll
        for (int ks = 0; ks < 4; ++ks) al[ks] = el8[(mt * 4 + ks) * 64 + lane];

        f32x16 acc0, acc1;
#pragma unroll
        for (int r = 0; r < 16; ++r) { acc0[r] = 0.0f; acc1[r] = 0.0f; }
#pragma unroll
        for (int ks = 0; ks < 5; ++ks) {
            acc0 = __builtin_amdgcn_mfma_f32_32x32x16_bf16(ah[ks], fah[ks], acc0, 0, 0, 0);
            acc1 = __builtin_amdgcn_mfma_f32_32x32x16_bf16(ah[ks], fbh[ks], acc1, 0, 0, 0);
        }
#pragma unroll
        for (int ks = 0; ks < 4; ++ks) {
            acc0 = __builtin_amdgcn_mfma_f32_32x32x16_bf16(al[ks], fah[ks], acc0, 0, 0, 0);
            acc1 = __builtin_amdgcn_mfma_f32_32x32x16_bf16(al[ks], fbh[ks], acc1, 0, 0, 0);
        }
#pragma unroll
        for (int ks = 0; ks < 4; ++ks) {
            acc0 = __builtin_amdgcn_mfma_f32_32x32x16_bf16(ah[ks], fal[ks], acc0, 0, 0, 0);
            acc1 = __builtin_amdgcn_mfma_f32_32x32x16_bf16(ah[ks], fbl[ks], acc1, 0, 0, 0);
        }

        int mb = mt * 32 + hv4;
#pragma unroll
        for (int r = 0; r < 16; ++r) {
            int mi = mb + (r & 3) + 8 * (r >> 2);
            {
                float s = acc0[r];
                bool c1 = s < s1a, c2 = s < s2a;
                s2a = c1 ? s1a : (c2 ? s : s2a); i2a = c1 ? i1a : (c2 ? mi : i2a);
                s1a = c1 ? s : s1a;              i1a = c1 ? mi : i1a;
            }
            {
                float s = acc1[r];
                bool c1 = s < s1b, c2 = s < s2b;
                s2b = c1 ? s1b : (c2 ? s : s2b); i2b = c1 ? i1b : (c2 ? mi : i2b);
                s1b = c1 ? s : s1b;              i1b = c1 ? mi : i1b;
            }
        }
    }

    // lanes l and l^32 hold disjoint code-rows of the same token column: merge
    merge2(s1a, i1a, s2a, i2a, __shfl_xor(s1a, 32), __shfl_xor(i1a, 32),
           __shfl_xor(s2a, 32), __shfl_xor(i2a, 32));
    merge2(s1b, i1b, s2b, i2b, __shfl_xor(s1b, 32), __shfl_xor(i1b, 32),
           __shfl_xor(s2b, 32), __shfl_xor(i2b, 32));

    bool hi = (lane & 32) != 0;
    int I1 = hi ? i1b : i1a;
    int I2 = hi ? i2b : i2a;

    // ---- exact fp32 rescore of the two candidates (codebook rows from LDS) ----
    int hw = wbase + lane;
    const float* xq = xp + hw;
    float xv[64];
#pragma unroll
    for (int c = 0; c < 64; ++c) xv[c] = xq[(size_t)c * HW];

    float sxx;
    {
        float d0 = 0.f, d1 = 0.f, d2 = 0.f, d3 = 0.f;
#pragma unroll
        for (int c = 0; c < 64; c += 4) {
            d0 = fmaf(xv[c], xv[c], d0);
            d1 = fmaf(xv[c + 1], xv[c + 1], d1);
            d2 = fmaf(xv[c + 2], xv[c + 2], d2);
            d3 = fmaf(xv[c + 3], xv[c + 3], d3);
        }
        sxx = (d0 + d1) + (d2 + d3);
    }

    int ia = (I1 < I2) ? I1 : I2;
    int ib = (I1 < I2) ? I2 : I1;
    const float* ra = se + ia * 66;
    const float* rb = se + ib * 66;
    float sa, sb;
    {
        float d0 = 0.f, d1 = 0.f, d2 = 0.f, d3 = 0.f;
#pragma unroll
        for (int c = 0; c < 64; c += 4) {
            float2 p0 = *(const float2*)&ra[c];
            float2 p1 = *(const float2*)&ra[c + 2];
            d0 = fmaf(xv[c], p0.x, d0);
            d1 = fmaf(xv[c + 1], p0.y, d1);
            d2 = fmaf(xv[c + 2], p1.x, d2);
            d3 = fmaf(xv[c + 3], p1.y, d3);
        }
        sa = (sxx + ra[64]) - 2.0f * ((d0 + d1) + (d2 + d3));
    }
    {
        float d0 = 0.f, d1 = 0.f, d2 = 0.f, d3 = 0.f;
#pragma unroll
        for (int c = 0; c < 64; c += 4) {
            float2 p0 = *(const float2*)&rb[c];
            float2 p1 = *(const float2*)&rb[c + 2];
            d0 = fmaf(xv[c], p0.x, d0);
            d1 = fmaf(xv[c + 1], p0.y, d1);
            d2 = fmaf(xv[c + 2], p1.x, d2);
            d3 = fmaf(xv[c + 3], p1.y, d3);
        }
        sb = (sxx + rb[64]) - 2.0f * ((d0 + d1) + (d2 + d3));
    }
    int win = (sb < sa) ? ib : ia;   // tie -> lower index (ia < ib)

    idx_out[tb + wv * 64 + lane] = (unsigned short)win;

    // quantized write + loss (code row from LDS)
    const float* rw = (win == ia) ? ra : rb;
    float* qp = qout + (size_t)n * 64 * HW + hw;
    float l0 = 0.f, l1 = 0.f, l2 = 0.f, l3 = 0.f;
#pragma unroll
    for (int c = 0; c < 64; c += 4) {
        float2 p0 = *(const float2*)&rw[c];
        float2 p1 = *(const float2*)&rw[c + 2];
        qp[(size_t)c * HW] = p0.x;
        qp[(size_t)(c + 1) * HW] = p0.y;
        qp[(size_t)(c + 2) * HW] = p1.x;
        qp[(size_t)(c + 3) * HW] = p1.y;
        float f0 = xv[c] - p0.x, f1 = xv[c + 1] - p0.y;
        float f2 = xv[c + 2] - p1.x, f3 = xv[c + 3] - p1.y;
        l0 = fmaf(f0, f0, l0);
        l1 = fmaf(f1, f1, l1);
        l2 = fmaf(f2, f2, l2);
        l3 = fmaf(f3, f3, l3);
    }
    float lp = (l0 + l1) + (l2 + l3);
#pragma unroll
    for (int off = 32; off; off >>= 1) lp += __shfl_down(lp, off);
    if (lane == 0) atomicAdd(loss_acc, lp);
}

// grid = (32 images) x (8 channel-groups) x (2 hw-halves) = 512 blocks.
// LDS acc [512][9] (9 coprime to 32 banks). 2 blocks/CU for latency overlap.
__global__ __launch_bounds__(1024) void k_seg(const float* __restrict__ x,
                                              const unsigned short* __restrict__ idx,
                                              float* __restrict__ cnt_g,
                                              float* __restrict__ avg_g) {
    __shared__ float acc[KC * 9];
    __shared__ float cnt[KC];
    int tid = threadIdx.x;
    int b = blockIdx.x;
    int n = b >> 4;
    int cg = (b >> 1) & 7;
    int h = b & 1;

    for (int i = tid; i < KC * 9; i += 1024) acc[i] = 0.f;
    if (cg == 0 && tid < KC) cnt[tid] = 0.f;
    __syncthreads();

    const float* xp = x + (size_t)n * 64 * HW + (size_t)(cg * 8) * HW + h * 2048;
    const unsigned short* ip = idx + n * HW + h * 2048;

#pragma unroll
    for (int p = 0; p < 2; ++p) {
        int hw = p * 1024 + tid;
        int k = ip[hw];
        if (cg == 0) atomicAdd(&cnt[k], 1.0f);
        float* row = acc + k * 9;
#pragma unroll
        for (int j = 0; j < 8; ++j) {
            atomicAdd(&row[j], xp[(size_t)j * HW + hw]);
        }
    }
    __syncthreads();

    for (int i = tid; i < KC * 8; i += 1024) {
        int k = i >> 3, j = i & 7;
        atomicAdd(&avg_g[k * 64 + cg * 8 + j], acc[k * 9 + j]);
    }
    if (cg == 0 && tid < KC) atomicAdd(&cnt_g[tid], cnt[tid]);
}

__global__ void k_fin(const float* __restrict__ cs_in, const float* __restrict__ avg_in,
                      const float* __restrict__ cnt, const float* __restrict__ avgacc,
                      const float* __restrict__ loss_acc,
                      float* __restrict__ loss_out, float* __restrict__ emb_out,
                      float* __restrict__ cs_out, float* __restrict__ avg_out) {
    int i = blockIdx.x * 256 + threadIdx.x;
    if (i >= KC * 64) return;
    int k = i >> 6, c = i & 63;
    float ncs = cs_in[k] * 0.99f + 0.01f * cnt[k];
    float nav = avg_in[i] * 0.99f + 0.01f * avgacc[i];
    avg_out[i] = nav;
    emb_out[i] = nav / (ncs + 1e-5f);
    if (c == 0) cs_out[k] = ncs;
    if (i == 0) loss_out[0] = loss_acc[0] * (1.0f / 8388608.0f);
}

extern "C" void kernel_launch(void* const* d_in, const int* in_sizes, int n_in,
                              void* d_out, int out_size, void* d_ws, size_t ws_size,
                              hipStream_t stream) {
    (void)in_sizes; (void)n_in; (void)out_size; (void)ws_size;
    const float* x   = (const float*)d_in[0];
    const float* emb = (const float*)d_in[1];
    const float* cs  = (const float*)d_in[2];
    const float* avg = (const float*)d_in[3];

    float* out      = (float*)d_out;
    float* qout     = out;
    float* loss_out = out + 8388608;
    float* emb_out  = loss_out + 1;
    float* cs_out   = emb_out + 32768;
    float* avg_out  = cs_out + 512;

    char* wsb = (char*)d_ws;
    float* cnt_acc  = (float*)wsb;
    float* avg_acc  = (float*)(wsb + 2048);
    float* loss_acc = (float*)(wsb + 133120);
    float* en       = (float*)(wsb + WS_EN);
    short* ehf      = (short*)(wsb + WS_EHF);
    short* elf      = (short*)(wsb + WS_ELF);
    unsigned short* idx = (unsigned short*)(wsb + WS_IDX);

    hipMemsetAsync(d_ws, 0, 133124, stream);
    k_prep_en<<<2, 256, 0, stream>>>(emb, en);
    k_prep_frag<<<16, 256, 0, stream>>>(emb, en, ehf, elf);
    k_main<<<256, 512, 0, stream>>>(x, ehf, elf, en, emb, qout, idx, loss_acc);
    k_seg<<<512, 1024, 0, stream>>>(x, idx, cnt_acc, avg_acc);
    k_fin<<<128, 256, 0, stream>>>(cs, avg, cnt_acc, avg_acc, loss_acc,
                                   loss_out, emb_out, cs_out, avg_out);
}